// Round 12
// baseline (36.331 us; speedup 1.0000x reference)
//
#include <hip/hip_runtime.h>
#include <hip/hip_fp16.h>
#include <string.h>

// Problem constants (SCALE=2, K=5, PATCH=3, STRIDE=1)
#define CY     64           // y channels
#define HY     80           // y spatial
#define HD     40           // yd spatial
#define SPD    (HD*HD)      // 1600
#define M1     78           // query patch grid dim
#define N1     38           // matched patch grid dim
#define M_TOT  (M1*M1)      // 6084
#define N_TOT  (N1*N1)      // 1444
#define KK     5
#define HS     160          // output spatial
#define EPSF   1e-5f
#define LP     33           // LDS row pitch (floats): 2-way max on both phases (free)
#define NU     54           // 3x18 patch union per block

typedef float f32x2 __attribute__((ext_vector_type(2)));

__device__ __forceinline__ unsigned pkf16(float a, float b) {
    __half2 h = __floats2half2_rn(a, b);
    unsigned u; memcpy(&u, &h, 4); return u;
}
__device__ __forceinline__ f32x2 upk2(unsigned u) {
    __half2 h; memcpy(&h, &u, 4);
    float2 f = __half22float2(h);
    f32x2 r; r.x = f.x; r.y = f.y; return r;
}

// Fused pre-pass, partitioned by flat thread id (all parts independent):
//  A: yd -> ydW[sp][cc] = uint4{ f16x4 @ sp, f16x4 @ sp+1 }  (dup-pair layout)
//  B: zstP[n][cc] = pack(mu, 1/sd) over 36 elems
//  C: ystP[m][cc] = pack(mu, sd) over 9 elems
__global__ __launch_bounds__(256) void pre_kernel(const float* __restrict__ y,
                                                  const float* __restrict__ yd,
                                                  uint4* __restrict__ ydW,
                                                  unsigned* __restrict__ zstP,
                                                  unsigned* __restrict__ ystP) {
    int id = blockIdx.x * 256 + threadIdx.x;
    if (id < SPD * 64) {                       // ---- A: transpose (coalesced writes)
        int cc = id & 63, sp = id >> 6;
        const float* b0 = yd + (cc * 4) * SPD + sp;
        int d = (sp < SPD - 1) ? 1 : 0;        // clamp pad (never consumed)
        ydW[sp * 64 + cc] = make_uint4(pkf16(b0[0], b0[SPD]),
                                       pkf16(b0[2*SPD], b0[3*SPD]),
                                       pkf16(b0[d], b0[SPD+d]),
                                       pkf16(b0[2*SPD+d], b0[3*SPD+d]));
        return;
    }
    id -= SPD * 64;
    if (id < N_TOT * 64) {                     // ---- B: z-stats
        int n  = id % N_TOT;                   // lanes = consecutive n -> coalesced reads
        int cc = id / N_TOT;
        int ni = n / N1, nj = n - ni * N1;
        const float* base = yd + (cc * 4) * SPD + ni * HD + nj;
        float s = 0.f, sq = 0.f;
#pragma unroll
        for (int r = 0; r < 4; ++r)
#pragma unroll
            for (int i = 0; i < 3; ++i)
#pragma unroll
                for (int j = 0; j < 3; ++j) {
                    float v = base[r * SPD + i * HD + j];
                    s += v; sq += v * v;
                }
        float mu  = s * (1.f / 36.f);
        float var = (sq - 36.f * mu * mu) * (1.f / 35.f);
        zstP[n * 64 + cc] = pkf16(mu, rsqrtf(var + EPSF));
        return;
    }
    id -= N_TOT * 64;
    if (id >= CY * M_TOT) return;              // ---- C: y-stats
    int m  = id % M_TOT;                       // lanes = consecutive m -> coalesced reads
    int cc = id / M_TOT;
    int mi = m / M1, mj = m - mi * M1;
    const float* base = y + cc * (HY * HY) + mi * HY + mj;
    float s = 0.f, sq = 0.f;
#pragma unroll
    for (int i = 0; i < 3; ++i)
#pragma unroll
        for (int j = 0; j < 3; ++j) {
            float v = base[i * HY + j];
            s += v; sq += v * v;
        }
    float mu  = s * (1.f / 9.f);
    float var = (sq - 9.f * mu * mu) * (1.f / 8.f);
    ystP[m * 64 + cc] = pkf16(mu, sqrtf(var + EPSF));
}

// Main: block = 8 waves; wave = TWO x-adjacent 2x2 quads at one (k, quad-row y), lanes = cc.
// NEW: cooperative LDS staging of the block's 3x18 patch-union coefficient table
// (a,b packed f16 per cc, + nsp scalars). Hot loop then has ONE VMEM level (yd only);
// coefs come from LDS; nsp scalars hoisted to SGPRs. Stats L2 traffic cut ~45%.
// Epilogue: LDS transpose (same buffer, after sync) -> full-line non-temporal stores.
__global__ __launch_bounds__(512) void agg_kernel(
    const uint4* __restrict__ ydW, const unsigned* __restrict__ zstP,
    const unsigned* __restrict__ ystP, const int* __restrict__ idx,
    float* __restrict__ out)
{
    __shared__ unsigned lds_u[128 * LP];       // 16,896 B; staging then epilogue (reused)

    int lane = threadIdx.x & 63;
    int w    = __builtin_amdgcn_readfirstlane(threadIdx.x >> 6);  // 0..7
    int bid  = blockIdx.x;                     // 0..1999
    int wg   = (bid & 7) * 250 + (bid >> 3);   // bijective XCD swizzle (2000 % 8 == 0)
    int k    = wg / 400;
    int rem  = wg - k * 400;
    int y    = rem / 5;                        // quad row 0..79
    int xb2  = rem - y * 5;                    // x super-block 0..4 (32 X pixels)
    int x0   = xb2 * 16 + w * 2;               // quad A col; quad B = x0+1

    // ---- Stage coef table for the 3x18 patch union: lds_u[u*64+cc] = pack(a,b),
    //      lds_u[3456+u] = nsp.  u = urow*18 + ucol; wave-uniform u -> coalesced loads.
    int row0 = y - 2, col0 = xb2 * 16 - 2;
    for (int t = threadIdx.x; t < NU * 64; t += 512) {
        int cc = t & 63, u = t >> 6;
        int mi = row0 + u / 18, mj = col0 + u % 18;
        if (mi >= 0 && mi < M1 && mj >= 0 && mj < M1) {
            int m = mi * M1 + mj;
            int n = idx[m * KK + k];           // wave-uniform
            f32x2 ys = upk2(ystP[m * 64 + cc]);
            f32x2 zs = upk2(zstP[n * 64 + cc]);
            float a = ys.y * zs.y;             // y_sd * inv_z_sd
            float b = fmaf(-zs.x, a, ys.x);    // y_mu - z_mu*a
            lds_u[u * 64 + cc] = pkf16(a, b);
            if (cc == 0) {
                int ni = n / N1;
                lds_u[NU * 64 + u] = (unsigned)(ni * HD + (n - ni * N1));
            }
        }
    }
    __syncthreads();

    f32x2 acc01[2] = {{0.f,0.f},{0.f,0.f}};    // dy0 row (r0,r1), quads A,B
    f32x2 acc23[2] = {{0.f,0.f},{0.f,0.f}};    // dy1 row (r2,r3)
    float bs[2] = {0.f, 0.f};
    float inv0, inv1;

    auto serve = [&](int q, unsigned lo, unsigned hi, float a, float b) {
        f32x2 am; am.x = a; am.y = a;
        acc01[q] = __builtin_elementwise_fma(am, upk2(lo), acc01[q]);
        acc23[q] = __builtin_elementwise_fma(am, upk2(hi), acc23[q]);
        bs[q] += b;
    };

    if (y >= 2 && y <= M1 - 1 && x0 >= 2 && x0 <= M1 - 2) {
        inv0 = inv1 = 1.f / 9.f;
        int spb[12];                           // nsp scalars -> SGPRs, up front
#pragma unroll
        for (int p = 0; p < 12; ++p)
            spb[p] = __builtin_amdgcn_readfirstlane(
                        (int)lds_u[NU * 64 + (p >> 2) * 18 + w * 2 + (p & 3)]);
#pragma unroll
        for (int r = 0; r < 3; ++r) {
            int roff = (2 - r) * HD;
            int s0 = spb[r*4+0] + roff, s1 = spb[r*4+1] + roff;
            int s2 = spb[r*4+2] + roff, s3 = spb[r*4+3] + roff;
            // yd loads: single VMEM level, SGPR bases + lane offset
            uint2 v0 = *(const uint2*)(ydW + (s0 + 2) * 64 + lane);  // A j=2
            uint4 v1 = ydW[(s1 + 1) * 64 + lane];                    // A j=1 | B j=2
            uint4 v2 = ydW[(s2 + 0) * 64 + lane];                    // A j=0 | B j=1
            uint2 v3 = *(const uint2*)(ydW + (s3 + 0) * 64 + lane);  // B j=0
            // coef from LDS (lane-consecutive -> conflict-free)
            int ub = (r * 18 + w * 2) * 64 + lane;
            f32x2 c0 = upk2(lds_u[ub]);
            f32x2 c1 = upk2(lds_u[ub + 64]);
            f32x2 c2 = upk2(lds_u[ub + 128]);
            f32x2 c3 = upk2(lds_u[ub + 192]);
            serve(0, v0.x, v0.y, c0.x, c0.y);
            serve(0, v1.x, v1.y, c1.x, c1.y);
            serve(1, v1.z, v1.w, c1.x, c1.y);
            serve(0, v2.x, v2.y, c2.x, c2.y);
            serve(1, v2.z, v2.w, c2.x, c2.y);
            serve(1, v3.x, v3.y, c3.x, c3.y);
        }
    } else {
#pragma unroll
        for (int q = 0; q < 2; ++q) {
            int x = x0 + q;
            int milo = max(0, y - 2), mihi = min(M1 - 1, y);
            int mjlo = max(0, x - 2), mjhi = min(M1 - 1, x);
            float iv = 1.f / (float)((mihi - milo + 1) * (mjhi - mjlo + 1));
            if (q == 0) inv0 = iv; else inv1 = iv;
            for (int mi = milo; mi <= mihi; ++mi)
                for (int mj = mjlo; mj <= mjhi; ++mj) {
                    int m = mi * M1 + mj;
                    int n = idx[m * KK + k];   // uniform -> s_load
                    f32x2 ys = upk2(ystP[m * 64 + lane]);
                    f32x2 zs = upk2(zstP[n * 64 + lane]);
                    float a = ys.y * zs.y;
                    float b = fmaf(-zs.x, a, ys.x);
                    int ni = n / N1;
                    int sp = ni * HD + (n - ni * N1) + (y - mi) * HD + (x - mj);
                    uint2 v = *(const uint2*)(ydW + sp * 64 + lane);
                    serve(q, v.x, v.y, a, b);
                }
        }
    }

    __syncthreads();                           // staging reads done; reuse LDS for epilogue

    // Stage: row = dy*64 + cc (128 rows), col = (w*2+q)*2 + dx (32 cols). Stride LP -> free 2-way.
    float* ldsf = (float*)lds_u;
#pragma unroll
    for (int q = 0; q < 2; ++q) {
        float iv = q ? inv1 : inv0;
        float bq = bs[q];
        int col = (w * 2 + q) * 2;
        ldsf[(0 * CY + lane) * LP + col]     = (acc01[q].x + bq) * iv;
        ldsf[(0 * CY + lane) * LP + col + 1] = (acc01[q].y + bq) * iv;
        ldsf[(1 * CY + lane) * LP + col]     = (acc23[q].x + bq) * iv;
        ldsf[(1 * CY + lane) * LP + col + 1] = (acc23[q].y + bq) * iv;
    }

    __syncthreads();

    // Drain: each wave-store = 2 rows x 32 cols = 2 x 128B full-line runs (non-temporal).
    int rsel = lane >> 5, c = lane & 31;
    int X0 = xb2 * 32, Y0 = 2 * y;
#pragma unroll
    for (int t = 0; t < 8; ++t) {
        int row = t * 16 + w * 2 + rsel;       // 0..127
        float v = ldsf[row * LP + c];
        int dy = row >> 6, cc = row & 63;
        __builtin_nontemporal_store(v,
            out + (((size_t)(k * CY + cc) * HS + (Y0 + dy)) * HS + X0 + c));
    }
}

extern "C" void kernel_launch(void* const* d_in, const int* in_sizes, int n_in,
                              void* d_out, int out_size, void* d_ws, size_t ws_size,
                              hipStream_t stream) {
    const float* y   = (const float*)d_in[0];
    const float* yd  = (const float*)d_in[1];
    const int*   idx = (const int*)d_in[2];
    float* out = (float*)d_out;

    char* ws = (char*)d_ws;
    uint4*    ydW  = (uint4*)ws;                             // 1,638,400 B
    unsigned* zstP = (unsigned*)(ws + 1638400);              //   369,664 B
    unsigned* ystP = (unsigned*)(ws + 2008064);              // 1,557,504 B

    int pre_total = SPD * 64 + N_TOT * 64 + CY * M_TOT;      // 584,192 -> 2283 blocks
    pre_kernel<<<(pre_total + 255) / 256, 256, 0, stream>>>(y, yd, ydW, zstP, ystP);
    agg_kernel<<<KK * 400, 512, 0, stream>>>(ydW, zstP, ystP, idx, out);
}

// Round 13
// 32.305 us; speedup vs baseline: 1.1246x; 1.1246x over previous
//
#include <hip/hip_runtime.h>
#include <hip/hip_fp16.h>
#include <string.h>

// Problem constants (SCALE=2, K=5, PATCH=3, STRIDE=1)
#define CY     64           // y channels
#define HY     80           // y spatial
#define HD     40           // yd spatial
#define SPD    (HD*HD)      // 1600
#define M1     78           // query patch grid dim
#define N1     38           // matched patch grid dim
#define M_TOT  (M1*M1)      // 6084
#define N_TOT  (N1*N1)      // 1444
#define KK     5
#define HS     160          // output spatial
#define EPSF   1e-5f
#define LP     17           // LDS row pitch (floats) for 16-col epilogue: 2-way max (free)

typedef float f32x2 __attribute__((ext_vector_type(2)));

__device__ __forceinline__ unsigned pkf16(float a, float b) {
    __half2 h = __floats2half2_rn(a, b);
    unsigned u; memcpy(&u, &h, 4); return u;
}
__device__ __forceinline__ f32x2 upk2(unsigned u) {
    __half2 h; memcpy(&h, &u, 4);
    float2 f = __half22float2(h);
    f32x2 r; r.x = f.x; r.y = f.y; return r;
}

// Fused pre-pass, partitioned by flat thread id (all parts independent):
//  A: yd -> ydW[sp][cc] = uint4{ f16x4 @ sp, f16x4 @ sp+1 }  (dup-pair layout)
//  B: zstP[n][cc] = pack(mu, 1/sd) over 36 elems
//  C: ystP[m][cc] = pack(mu, sd) over 9 elems
__global__ __launch_bounds__(256) void pre_kernel(const float* __restrict__ y,
                                                  const float* __restrict__ yd,
                                                  uint4* __restrict__ ydW,
                                                  unsigned* __restrict__ zstP,
                                                  unsigned* __restrict__ ystP) {
    int id = blockIdx.x * 256 + threadIdx.x;
    if (id < SPD * 64) {                       // ---- A: transpose (coalesced writes)
        int cc = id & 63, sp = id >> 6;
        const float* b0 = yd + (cc * 4) * SPD + sp;
        int d = (sp < SPD - 1) ? 1 : 0;        // clamp pad (never consumed)
        ydW[sp * 64 + cc] = make_uint4(pkf16(b0[0], b0[SPD]),
                                       pkf16(b0[2*SPD], b0[3*SPD]),
                                       pkf16(b0[d], b0[SPD+d]),
                                       pkf16(b0[2*SPD+d], b0[3*SPD+d]));
        return;
    }
    id -= SPD * 64;
    if (id < N_TOT * 64) {                     // ---- B: z-stats
        int n  = id % N_TOT;                   // lanes = consecutive n -> coalesced reads
        int cc = id / N_TOT;
        int ni = n / N1, nj = n - ni * N1;
        const float* base = yd + (cc * 4) * SPD + ni * HD + nj;
        float s = 0.f, sq = 0.f;
#pragma unroll
        for (int r = 0; r < 4; ++r)
#pragma unroll
            for (int i = 0; i < 3; ++i)
#pragma unroll
                for (int j = 0; j < 3; ++j) {
                    float v = base[r * SPD + i * HD + j];
                    s += v; sq += v * v;
                }
        float mu  = s * (1.f / 36.f);
        float var = (sq - 36.f * mu * mu) * (1.f / 35.f);
        zstP[n * 64 + cc] = pkf16(mu, rsqrtf(var + EPSF));
        return;
    }
    id -= N_TOT * 64;
    if (id >= CY * M_TOT) return;              // ---- C: y-stats
    int m  = id % M_TOT;                       // lanes = consecutive m -> coalesced reads
    int cc = id / M_TOT;
    int mi = m / M1, mj = m - mi * M1;
    const float* base = y + cc * (HY * HY) + mi * HY + mj;
    float s = 0.f, sq = 0.f;
#pragma unroll
    for (int i = 0; i < 3; ++i)
#pragma unroll
        for (int j = 0; j < 3; ++j) {
            float v = base[i * HY + j];
            s += v; sq += v * v;
        }
    float mu  = s * (1.f / 9.f);
    float var = (sq - 9.f * mu * mu) * (1.f / 8.f);
    ystP[m * 64 + cc] = pkf16(mu, sqrtf(var + EPSF));
}

// Main: block = 4 waves (256 threads); wave = TWO x-adjacent 2x2 quads at one (k, quad-row y),
// lanes = cc. Smaller block = finer scheduling quantum, 4-wave barrier coupling, 8.7KB LDS.
// Coef computed INLINE per patch (uniform idx s_load -> stats wave-loads -> (a,b));
// 12 yd issues (2x uint4 + 2x uint2 per row), f32x2 pk-fma accumulators.
// Epilogue: LDS transpose over 16-pixel X span -> full-line (64B) non-temporal stores.
__global__ __launch_bounds__(256) void agg_kernel(
    const uint4* __restrict__ ydW, const unsigned* __restrict__ zstP,
    const unsigned* __restrict__ ystP, const int* __restrict__ idx,
    float* __restrict__ out)
{
    __shared__ float lds[128 * LP];            // 8,704 B

    int lane = threadIdx.x & 63;
    int w    = __builtin_amdgcn_readfirstlane(threadIdx.x >> 6);  // 0..3
    int bid  = blockIdx.x;                     // 0..3999
    int wg   = (bid & 7) * 500 + (bid >> 3);   // bijective XCD swizzle (4000 % 8 == 0)
    int k    = wg / 800;
    int rem  = wg - k * 800;
    int y    = rem / 10;                       // quad row 0..79
    int xb   = rem - y * 10;                   // x block 0..9 (16 X pixels)
    int x0   = xb * 8 + w * 2;                 // quad A col; quad B = x0+1

    f32x2 acc01[2] = {{0.f,0.f},{0.f,0.f}};    // dy0 row (r0,r1), quads A,B
    f32x2 acc23[2] = {{0.f,0.f},{0.f,0.f}};    // dy1 row (r2,r3)
    float bs[2] = {0.f, 0.f};
    float inv0, inv1;

    auto serve = [&](f32x2& a01, f32x2& a23, float& bsum,
                     unsigned lo, unsigned hi, float a, float b) {
        f32x2 am; am.x = a; am.y = a;
        a01 = __builtin_elementwise_fma(am, upk2(lo), a01);
        a23 = __builtin_elementwise_fma(am, upk2(hi), a23);
        bsum += b;
    };

    if (y >= 2 && y <= M1 - 1 && x0 >= 2 && x0 <= M1 - 2) {
        inv0 = inv1 = 1.f / 9.f;
        unsigned ysu[12], zsu[12];
        int nn[12];
#pragma unroll
        for (int p = 0; p < 12; ++p) {         // all independent, issued up front
            int m = (y - 2 + (p >> 2)) * M1 + (x0 - 2 + (p & 3));
            nn[p]  = idx[m * KK + k];          // uniform -> s_load
            ysu[p] = ystP[m * 64 + lane];
        }
#pragma unroll
        for (int p = 0; p < 12; ++p)
            zsu[p] = zstP[nn[p] * 64 + lane];
        float aa[12], bb[12];
        int spb[12];
#pragma unroll
        for (int p = 0; p < 12; ++p) {
            f32x2 ys = upk2(ysu[p]), zs = upk2(zsu[p]);
            aa[p] = ys.y * zs.y;               // y_sd * inv_z_sd
            bb[p] = fmaf(-zs.x, aa[p], ys.x);  // y_mu - z_mu*a
            int n = nn[p], ni = n / N1;        // scalar arithmetic
            spb[p] = ni * HD + (n - ni * N1);
        }
#pragma unroll
        for (int r = 0; r < 3; ++r) {
            int roff = (2 - r) * HD;
            int s0 = spb[r*4+0] + roff, s1 = spb[r*4+1] + roff;
            int s2 = spb[r*4+2] + roff, s3 = spb[r*4+3] + roff;
            uint2 v0 = *(const uint2*)(ydW + (s0 + 2) * 64 + lane);  // A j=2
            uint4 v1 = ydW[(s1 + 1) * 64 + lane];                    // A j=1 | B j=2
            uint4 v2 = ydW[(s2 + 0) * 64 + lane];                    // A j=0 | B j=1
            uint2 v3 = *(const uint2*)(ydW + (s3 + 0) * 64 + lane);  // B j=0
            serve(acc01[0], acc23[0], bs[0], v0.x, v0.y, aa[r*4+0], bb[r*4+0]);
            serve(acc01[0], acc23[0], bs[0], v1.x, v1.y, aa[r*4+1], bb[r*4+1]);
            serve(acc01[1], acc23[1], bs[1], v1.z, v1.w, aa[r*4+1], bb[r*4+1]);
            serve(acc01[0], acc23[0], bs[0], v2.x, v2.y, aa[r*4+2], bb[r*4+2]);
            serve(acc01[1], acc23[1], bs[1], v2.z, v2.w, aa[r*4+2], bb[r*4+2]);
            serve(acc01[1], acc23[1], bs[1], v3.x, v3.y, aa[r*4+3], bb[r*4+3]);
        }
    } else {
#pragma unroll
        for (int q = 0; q < 2; ++q) {
            int x = x0 + q;
            int milo = max(0, y - 2), mihi = min(M1 - 1, y);
            int mjlo = max(0, x - 2), mjhi = min(M1 - 1, x);
            float iv = 1.f / (float)((mihi - milo + 1) * (mjhi - mjlo + 1));
            if (q == 0) inv0 = iv; else inv1 = iv;
            for (int mi = milo; mi <= mihi; ++mi)
                for (int mj = mjlo; mj <= mjhi; ++mj) {
                    int m = mi * M1 + mj;
                    int n = idx[m * KK + k];   // uniform -> s_load
                    f32x2 ys = upk2(ystP[m * 64 + lane]);
                    f32x2 zs = upk2(zstP[n * 64 + lane]);
                    float a = ys.y * zs.y;
                    float b = fmaf(-zs.x, a, ys.x);
                    int ni = n / N1;
                    int sp = ni * HD + (n - ni * N1) + (y - mi) * HD + (x - mj);
                    uint2 v = *(const uint2*)(ydW + sp * 64 + lane);
                    if (q == 0) serve(acc01[0], acc23[0], bs[0], v.x, v.y, a, b);
                    else        serve(acc01[1], acc23[1], bs[1], v.x, v.y, a, b);
                }
        }
    }

    // Stage: row = dy*64 + cc (128 rows), col = (w*2+q)*2 + dx (16 cols). Stride LP=17 -> free 2-way.
#pragma unroll
    for (int q = 0; q < 2; ++q) {
        float iv = q ? inv1 : inv0;
        float bq = bs[q];
        int col = (w * 2 + q) * 2;
        lds[(0 * CY + lane) * LP + col]     = (acc01[q].x + bq) * iv;
        lds[(0 * CY + lane) * LP + col + 1] = (acc01[q].y + bq) * iv;
        lds[(1 * CY + lane) * LP + col]     = (acc23[q].x + bq) * iv;
        lds[(1 * CY + lane) * LP + col + 1] = (acc23[q].y + bq) * iv;
    }

    __syncthreads();

    // Drain: 128 rows x 16 cols; each 16-lane group writes one FULL 64B line (non-temporal).
    int q  = lane >> 4;                        // 0..3
    int xi = lane & 15;                        // 0..15
    int X0 = xb * 16, Y0 = 2 * y;
#pragma unroll
    for (int t = 0; t < 8; ++t) {
        int row = t * 16 + w * 4 + q;          // 0..127
        float v = lds[row * LP + xi];
        int dy = row >> 6, cc = row & 63;
        __builtin_nontemporal_store(v,
            out + (((size_t)(k * CY + cc) * HS + (Y0 + dy)) * HS + X0 + xi));
    }
}

extern "C" void kernel_launch(void* const* d_in, const int* in_sizes, int n_in,
                              void* d_out, int out_size, void* d_ws, size_t ws_size,
                              hipStream_t stream) {
    const float* y   = (const float*)d_in[0];
    const float* yd  = (const float*)d_in[1];
    const int*   idx = (const int*)d_in[2];
    float* out = (float*)d_out;

    char* ws = (char*)d_ws;
    uint4*    ydW  = (uint4*)ws;                             // 1,638,400 B
    unsigned* zstP = (unsigned*)(ws + 1638400);              //   369,664 B
    unsigned* ystP = (unsigned*)(ws + 2008064);              // 1,557,504 B

    int pre_total = SPD * 64 + N_TOT * 64 + CY * M_TOT;      // 584,192 -> 2283 blocks
    pre_kernel<<<(pre_total + 255) / 256, 256, 0, stream>>>(y, yd, ydW, zstP, ystP);
    agg_kernel<<<KK * 800, 256, 0, stream>>>(ydW, zstP, ystP, idx, out);
}